// Round 7
// baseline (248.927 us; speedup 1.0000x reference)
//
#include <hip/hip_runtime.h>

// AdaptiveAttention: softmax is shift-invariant along the reduced axis, so
// out = softmax(alpha * QK^T) @ V. Two kernels:
//  1) prepass: K -> bf16 XOR-swizzled 16B granules (conflict-free LDS MFMA
//     reads); V -> transposed bf16 in a COALESCED-FRAGMENT layout: granule
//     (dim, ch) at index ((dim>>4)*2 + (ch>>2))*64 + (ch&3)*16 + (dim&15),
//     so a wave's (dt,c) fragment load is 1KB of contiguous global memory.
//     (R6 bug: block index used dt*4+c -> wrote past the V plane into the
//      next tile's K. ch has only 2 chunks of 4: block = dt*2+c.)
//  2) attention: BQ=128 (32 q/wave). K staged to LDS via double-buffered
//     global_load_lds (16KB/tile); V fragments read DIRECTLY from L2-resident
//     ws into registers (preloaded at top of iter, latency hidden by S-MFMAs)
//     -- LDS pipe was the widest consumer at R5. 2-pass Khi*(Qhi+Qlo) QK^T,
//     unnormalized exp2 softmax (bounded logits), MFMA PV, /l in epilogue.
// ws requirement: 32 heads * 32 ktiles * 32KB = 32 MB.

#define S_LEN 2048
#define HD    128
#define BQ    128
#define BK    64
#define NW    4
#define NT    (S_LEN / BK)   // 32 k-tiles
#define TILE_USH 16384       // per (head,kt): K 8192 | Vt 8192 ushorts

typedef __bf16 bf16x8 __attribute__((ext_vector_type(8)));
typedef __bf16 bf16x4 __attribute__((ext_vector_type(4)));
typedef float  f32x4  __attribute__((ext_vector_type(4)));

__device__ __forceinline__ unsigned short f2bf(float x) {
  unsigned u = __builtin_bit_cast(unsigned, x);
  u = (u + 0x7FFFu + ((u >> 16) & 1u)) >> 16;   // RNE
  return (unsigned short)u;
}
__device__ __forceinline__ float bf2f(unsigned short h) {
  unsigned u = ((unsigned)h) << 16;
  return __builtin_bit_cast(float, u);
}
__device__ __forceinline__ float fast_exp2(float x) {
#if __has_builtin(__builtin_amdgcn_exp2f)
  return __builtin_amdgcn_exp2f(x);
#else
  return exp2f(x);
#endif
}

// ---------- prepass: convert + transpose into ws ----------
__global__ __launch_bounds__(256) void attn_prepass_kernel(
    const float* __restrict__ kg, const float* __restrict__ vg,
    unsigned short* __restrict__ ws) {
  const int blk  = blockIdx.x;          // head*32 + kt
  const int head = blk >> 5;
  const int kt   = blk & 31;
  const int tid  = threadIdx.x;
  const size_t hoff = (size_t)head * S_LEN * HD;
  const float* kp = kg + hoff + (size_t)kt * BK * HD;
  const float* vp = vg + hoff + (size_t)kt * BK * HD;
  unsigned short* wsK  = ws + (size_t)blk * TILE_USH;
  unsigned short* wsVt = wsK + 8192;

  // K: granule (key, ch) = dims [ch*8, ch*8+8) of row key.
  // slot = (ch&8) | ((ch&7) ^ (key&7))  -> conflict-free b128 LDS reads.
#pragma unroll
  for (int it = 0; it < 4; ++it) {
    int idx = it * 256 + tid;           // 0..1023
    int key = idx >> 4;
    int ch  = idx & 15;
    const float* src = kp + key * HD + ch * 8;
    float4 a = *(const float4*)src;
    float4 b = *(const float4*)(src + 4);
    float xs[8] = {a.x, a.y, a.z, a.w, b.x, b.y, b.z, b.w};
    union { unsigned short s[8]; uint4 v; } hi;
#pragma unroll
    for (int j = 0; j < 8; ++j) hi.s[j] = f2bf(xs[j]);
    int slot = (ch & 8) | ((ch & 7) ^ (key & 7));
    *(uint4*)&wsK[key * 128 + slot * 8] = hi.v;
  }

  // V^T: granule (dim, ch) = keys [ch*8, ch*8+8) of column dim, stored at
  // granule index ((dim>>4)*2 + (ch>>2))*64 + (ch&3)*16 + (dim&15) so the
  // attention wave's (dt,c) fragment load is contiguous (lane = g*16+qi,
  // granule block = dt*2 + c, within-block = g*16 + qi).
#pragma unroll
  for (int it = 0; it < 4; ++it) {
    int idx = it * 256 + tid;           // 0..1023
    int ch  = idx >> 7;                 // 0..7
    int dim = idx & 127;
    union { unsigned short s[8]; uint4 v; } g;
#pragma unroll
    for (int j = 0; j < 8; ++j)
      g.s[j] = f2bf(vp[(size_t)(ch * 8 + j) * HD + dim]);
    int gran = ((dim >> 4) * 2 + (ch >> 2)) * 64 + (ch & 3) * 16 + (dim & 15);
    *(uint4*)&wsVt[gran * 8] = g.v;
  }
}

// ---------- attention ----------
__device__ __forceinline__ void stage_tile(const unsigned short* __restrict__ wt,
                                           unsigned short* dst, int tid, int w) {
  // 4 rounds x 256 lanes x 16B = 16KB (K plane only). LDS dest is
  // wave-uniform base + lane*16B -- the m104/m108 requirement.
#pragma unroll
  for (int r = 0; r < 4; ++r) {
    const unsigned int* gp = (const unsigned int*)(wt + (size_t)(r * 256 + tid) * 8);
    unsigned short* lp = dst + (size_t)(r * 256 + w * 64) * 8;
    __builtin_amdgcn_global_load_lds(
        (const __attribute__((address_space(1))) unsigned int*)gp,
        (__attribute__((address_space(3))) unsigned int*)lp, 16, 0, 0);
  }
}

__global__ __launch_bounds__(256, 2) void adaptive_attn_kernel(
    const float* __restrict__ qg, const unsigned short* __restrict__ ws,
    const float* __restrict__ alphap, float* __restrict__ out) {
  __shared__ unsigned short sBuf[2][8192];       // 32 KB K double buffer
  __shared__ unsigned short sP[NW][2][1024];     // 16 KB per wave/half, swizzled
  // 48 KB total

  const int b    = blockIdx.x;                   // 512 blocks
  const int head = (b & 7) * 4 + ((b >> 3) & 3); // XCD L2 locality swizzle
  const int qt   = b >> 5;                       // 0..15

  const int tid  = threadIdx.x;
  const int w    = tid >> 6;
  const int lane = tid & 63;
  const int g    = lane >> 4;
  const int qi   = lane & 15;

  const float lscale = alphap[0] * 1.44269504088896f;  // alpha * log2(e)

  // Q fragments (B-operand layout) for both query halves, (lscale*Q) hi/lo.
  bf16x8 qhi[2][4], qlo[2][4];
#pragma unroll
  for (int h = 0; h < 2; ++h) {
    const int qrow = qt * BQ + w * 32 + h * 16 + qi;
    const float* qp = qg + (size_t)head * S_LEN * HD + (size_t)qrow * HD;
#pragma unroll
    for (int c = 0; c < 4; ++c) {
      float4 a  = *(const float4*)(qp + c * 32 + g * 8);
      float4 bb = *(const float4*)(qp + c * 32 + g * 8 + 4);
      float xs[8] = {a.x, a.y, a.z, a.w, bb.x, bb.y, bb.z, bb.w};
      union { bf16x8 v; unsigned short s[8]; } hh, ll;
#pragma unroll
      for (int j = 0; j < 8; ++j) {
        float sx = xs[j] * lscale;
        hh.s[j] = f2bf(sx);
        ll.s[j] = f2bf(sx - bf2f(hh.s[j]));
      }
      qhi[h][c] = hh.v; qlo[h][c] = ll.v;
    }
  }

  f32x4 o[2][8];
#pragma unroll
  for (int h = 0; h < 2; ++h)
#pragma unroll
    for (int dt = 0; dt < 8; ++dt) o[h][dt] = (f32x4){0.f, 0.f, 0.f, 0.f};
  float lrun[2] = {0.f, 0.f};

  const unsigned short* wsh = ws + (size_t)head * NT * TILE_USH;

  // Prologue: stage K-tile 0 into buffer 0.
  stage_tile(wsh, &sBuf[0][0], tid, w);
  __syncthreads();

  for (int kt = 0; kt < NT; ++kt) {
    const unsigned short* sK = &sBuf[kt & 1][0];
    const unsigned short* wV = wsh + (size_t)kt * TILE_USH + 8192;

    // Prefetch next K-tile; its vmcnt drain hides behind compute.
    if (kt + 1 < NT)
      stage_tile(wsh + (size_t)(kt + 1) * TILE_USH, &sBuf[(kt + 1) & 1][0], tid, w);

    // Preload this tile's V fragments from L2-resident ws (coalesced 1KB per
    // (dt,c) load). Issued before S-phase so ~1000cyc of MFMA hides latency.
    bf16x8 vfr[8][2];
#pragma unroll
    for (int dt = 0; dt < 8; ++dt)
#pragma unroll
      for (int c = 0; c < 2; ++c)
        vfr[dt][c] = *(const bf16x8*)&wV[(size_t)((dt * 2 + c) * 64 + lane) * 8];

    // S^T (64 keys x 32 queries): each K fragment read feeds 4 MFMAs
    // (hi/lo pass x 2 query halves). key&7 == qi&7 since key = mt*16+qi.
    f32x4 st[2][4];
#pragma unroll
    for (int mt = 0; mt < 4; ++mt) {
      f32x4 a0 = (f32x4){0.f, 0.f, 0.f, 0.f};
      f32x4 a1 = (f32x4){0.f, 0.f, 0.f, 0.f};
#pragma unroll
      for (int c = 0; c < 4; ++c) {
        int ch   = c * 4 + g;
        int slot = (ch & 8) | ((ch & 7) ^ (qi & 7));
        bf16x8 ah = *(const bf16x8*)&sK[(mt * 16 + qi) * 128 + slot * 8];
        a0 = __builtin_amdgcn_mfma_f32_16x16x32_bf16(ah, qhi[0][c], a0, 0, 0, 0);
        a0 = __builtin_amdgcn_mfma_f32_16x16x32_bf16(ah, qlo[0][c], a0, 0, 0, 0);
        a1 = __builtin_amdgcn_mfma_f32_16x16x32_bf16(ah, qhi[1][c], a1, 0, 0, 0);
        a1 = __builtin_amdgcn_mfma_f32_16x16x32_bf16(ah, qlo[1][c], a1, 0, 0, 0);
      }
      st[0][mt] = a0; st[1][mt] = a1;
    }

    // Unnormalized softmax: p = exp2(st) (bounded logits; /l at the end).
    // P^T -> A-layout via per-wave per-half XOR-swizzled LDS staging.
#pragma unroll
    for (int h = 0; h < 2; ++h) {
      unsigned short* sPh = &sP[w][h][0];
#pragma unroll
      for (int mt = 0; mt < 4; ++mt) {
        float p0 = fast_exp2(st[h][mt][0]);
        float p1 = fast_exp2(st[h][mt][1]);
        float p2 = fast_exp2(st[h][mt][2]);
        float p3 = fast_exp2(st[h][mt][3]);
        lrun[h] += (p0 + p1) + (p2 + p3);
        bf16x4 pv4;
        pv4[0] = (__bf16)p0; pv4[1] = (__bf16)p1;
        pv4[2] = (__bf16)p2; pv4[3] = (__bf16)p3;
        int slot = (mt * 2 + (g >> 1)) ^ (qi & 7);
        *(bf16x4*)&sPh[qi * 64 + slot * 8 + (g & 1) * 4] = pv4;
      }
    }

    bf16x8 pf[2][2];
#pragma unroll
    for (int h = 0; h < 2; ++h)
#pragma unroll
      for (int c = 0; c < 2; ++c) {
        int slot = (c * 4 + g) ^ (qi & 7);   // read granule = c*4+g (8 keys)
        pf[h][c] = *(const bf16x8*)&sP[w][h][qi * 64 + slot * 8];
      }

    // PV: V fragments already in registers; each feeds both query halves.
#pragma unroll
    for (int dt = 0; dt < 8; ++dt) {
      f32x4 a0 = o[0][dt];
      f32x4 a1 = o[1][dt];
#pragma unroll
      for (int c = 0; c < 2; ++c) {
        a0 = __builtin_amdgcn_mfma_f32_16x16x32_bf16(pf[0][c], vfr[dt][c], a0, 0, 0, 0);
        a1 = __builtin_amdgcn_mfma_f32_16x16x32_bf16(pf[1][c], vfr[dt][c], a1, 0, 0, 0);
      }
      o[0][dt] = a0; o[1][dt] = a1;
    }

    // One barrier per iteration: (a) all K reads of buf[kt&1] done before
    // iteration kt+1 prefetches kt+2 into it; (b) drains the kt+1 DMA.
    __syncthreads();
  }

  // Epilogue: reduce l across quads, divide, store fp32.
  float* oph = out + (size_t)head * S_LEN * HD + (size_t)(qt * BQ + w * 32) * HD;
#pragma unroll
  for (int h = 0; h < 2; ++h) {
    float ltot = lrun[h];
    ltot += __shfl_xor(ltot, 16, 64);
    ltot += __shfl_xor(ltot, 32, 64);  // lanes with same qi hold l(query qi)
    float inv[4];
#pragma unroll
    for (int r = 0; r < 4; ++r) {
      float lr = __shfl(ltot, g * 4 + r, 64);
      inv[r] = 1.0f / lr;
    }
    float* op = oph + (size_t)(h * 16) * HD;
#pragma unroll
    for (int dt = 0; dt < 8; ++dt) {
#pragma unroll
      for (int r = 0; r < 4; ++r) {
        op[(size_t)(g * 4 + r) * HD + dt * 16 + qi] = o[h][dt][r] * inv[r];
      }
    }
  }
}

extern "C" void kernel_launch(void* const* d_in, const int* in_sizes, int n_in,
                              void* d_out, int out_size, void* d_ws, size_t ws_size,
                              hipStream_t stream) {
  const float* q     = (const float*)d_in[0];
  const float* k     = (const float*)d_in[1];
  const float* v     = (const float*)d_in[2];
  const float* alpha = (const float*)d_in[3];
  float* out = (float*)d_out;
  unsigned short* ws = (unsigned short*)d_ws;   // needs 32 MB

  hipLaunchKernelGGL(attn_prepass_kernel, dim3(1024), dim3(256), 0, stream,
                     k, v, ws);
  hipLaunchKernelGGL(adaptive_attn_kernel, dim3(512), dim3(256), 0, stream,
                     q, ws, alpha, out);
}